// Round 1
// baseline (807.130 us; speedup 1.0000x reference)
//
#include <hip/hip_runtime.h>
#include <hip/hip_bf16.h>

#define T_DIM 512
#define B_DIM 16
#define D_DIM 1024
#define N_DIM 512

// c-fold: store S' = C*S so the exp2 argument is a single fma.
// C = 2*log2(e); tanh via exp2: tanh(x) = 1 - 2/(exp2(C*x)+1)
#define C_FOLD  2.885390082f
#define INV_C   0.3465735903f

typedef short s16x8 __attribute__((ext_vector_type(8)));
typedef float f32x4 __attribute__((ext_vector_type(4)));
typedef float f32x2 __attribute__((ext_vector_type(2)));

__device__ __forceinline__ unsigned short f2bf(float f) {
    unsigned u = __float_as_uint(f);
    unsigned r = (u + 0x7fffu + ((u >> 16) & 1u)) >> 16;
    return (unsigned short)r;
}

// sum over the 32 lanes of this half-wave, result broadcast to all 32.
// xor1/xor2 via quad_perm, xor4/xor8 via row_ror (VALU pipe), xor16 via one
// ds_swizzle. Proven in R3 (passed, 713us).
__device__ __forceinline__ float half32_sum(float x) {
    x += __int_as_float(__builtin_amdgcn_update_dpp(0, __float_as_int(x), 0xB1,  0xf, 0xf, true)); // quad_perm[1,0,3,2]
    x += __int_as_float(__builtin_amdgcn_update_dpp(0, __float_as_int(x), 0x4E,  0xf, 0xf, true)); // quad_perm[2,3,0,1]
    x += __int_as_float(__builtin_amdgcn_update_dpp(0, __float_as_int(x), 0x124, 0xf, 0xf, true)); // row_ror:4
    x += __int_as_float(__builtin_amdgcn_update_dpp(0, __float_as_int(x), 0x128, 0xf, 0xf, true)); // row_ror:8
    x += __int_as_float(__builtin_amdgcn_ds_swizzle(__float_as_int(x), 0x401F));                   // xor 16
    return x;
}

// ---------------- projection GEMM: C[m,n] = sum_d x[m,d] * W[n,d] ----------
__global__ __launch_bounds__(256) void proj_gemm(
    const float* __restrict__ x,
    const float* __restrict__ Wk,
    const float* __restrict__ Wv,
    const float* __restrict__ Wq,
    float* __restrict__ kbuf, float* __restrict__ vbuf, float* __restrict__ qbuf)
{
    const float* W = (blockIdx.z == 0) ? Wk : (blockIdx.z == 1) ? Wv : Wq;
    float* out = (blockIdx.z == 0) ? kbuf : (blockIdx.z == 1) ? vbuf : qbuf;

    __shared__ __align__(16) unsigned short As[64 * 40];
    __shared__ __align__(16) unsigned short Bs[64 * 40];

    const int tid  = threadIdx.x;
    const int m0   = blockIdx.x * 64;
    const int n0   = blockIdx.y * 64;
    const int wave = tid >> 6;
    const int lane = tid & 63;
    const int l15  = lane & 15;
    const int quad = lane >> 4;

    const int srow = tid >> 2;
    const int scol = (tid & 3) * 8;

    f32x4 acc[4];
#pragma unroll
    for (int i = 0; i < 4; ++i) acc[i] = (f32x4)0.0f;

    for (int k0 = 0; k0 < D_DIM; k0 += 32) {
        __syncthreads();
        {
            const float* srcA = &x[(size_t)(m0 + srow) * D_DIM + k0 + scol];
            float4 a0 = *(const float4*)srcA;
            float4 a1 = *(const float4*)(srcA + 4);
            uint4 pa;
            pa.x = (unsigned)f2bf(a0.x) | ((unsigned)f2bf(a0.y) << 16);
            pa.y = (unsigned)f2bf(a0.z) | ((unsigned)f2bf(a0.w) << 16);
            pa.z = (unsigned)f2bf(a1.x) | ((unsigned)f2bf(a1.y) << 16);
            pa.w = (unsigned)f2bf(a1.z) | ((unsigned)f2bf(a1.w) << 16);
            *(uint4*)&As[srow * 40 + scol] = pa;

            const float* srcB = &W[(size_t)(n0 + srow) * D_DIM + k0 + scol];
            float4 b0 = *(const float4*)srcB;
            float4 b1 = *(const float4*)(srcB + 4);
            uint4 pb;
            pb.x = (unsigned)f2bf(b0.x) | ((unsigned)f2bf(b0.y) << 16);
            pb.y = (unsigned)f2bf(b0.z) | ((unsigned)f2bf(b0.w) << 16);
            pb.z = (unsigned)f2bf(b1.x) | ((unsigned)f2bf(b1.y) << 16);
            pb.w = (unsigned)f2bf(b1.z) | ((unsigned)f2bf(b1.w) << 16);
            *(uint4*)&Bs[srow * 40 + scol] = pb;
        }
        __syncthreads();
        s16x8 af = *(const s16x8*)&As[(wave * 16 + l15) * 40 + quad * 8];
#pragma unroll
        for (int nt = 0; nt < 4; ++nt) {
            s16x8 bf = *(const s16x8*)&Bs[(nt * 16 + l15) * 40 + quad * 8];
            acc[nt] = __builtin_amdgcn_mfma_f32_16x16x32_bf16(af, bf, acc[nt], 0, 0, 0);
        }
    }
#pragma unroll
    for (int nt = 0; nt < 4; ++nt) {
#pragma unroll
        for (int rg = 0; rg < 4; ++rg) {
            int row = m0 + wave * 16 + quad * 4 + rg;
            int col = n0 + nt * 16 + l15;
            out[(size_t)row * N_DIM + col] = acc[nt][rg];
        }
    }
}

// ---------------- k row-normalization (in place) ---------------------------
__global__ __launch_bounds__(256) void knorm(float* __restrict__ kbuf)
{
    const int wave = threadIdx.x >> 6;
    const int lane = threadIdx.x & 63;
    const int row  = blockIdx.x * 4 + wave;
    float* p = &kbuf[(size_t)row * N_DIM + lane * 8];
    float4 a = *(const float4*)p;
    float4 b = *(const float4*)(p + 4);
    float s = a.x*a.x + a.y*a.y + a.z*a.z + a.w*a.w
            + b.x*b.x + b.y*b.y + b.z*b.z + b.w*b.w;
#pragma unroll
    for (int m = 1; m < 64; m <<= 1) s += __shfl_xor(s, m, 64);
    float inv = 1.0f / (sqrtf(s) + 1e-6f);
    a.x *= inv; a.y *= inv; a.z *= inv; a.w *= inv;
    b.x *= inv; b.y *= inv; b.z *= inv; b.w *= inv;
    *(float4*)p = a;
    *(float4*)(p + 4) = b;
}

// ---------------- sequential scan ------------------------------------------
// grid(64, 16): x = 8-row chunk, y = batch. block 256 (4 waves = 8 halves).
// R4 change: 8 rows/block instead of 16 -> 1024 blocks = 4 blocks/CU =
// 16 waves/CU (was 2 blocks/CU, Occupancy 19.9%, VALUBusy 73.9%). The scan
// is issue/latency-bound on the VALU+trans pipes (exp2+rcp per element);
// doubling resident waves per SIMD (2->4) hides the per-step serial chain
// (matvec -> DPP reduce -> exp2/rcp update) and the barrier bubbles.
// Each 32-lane half owns ONE row (r0 = tid>>5) x 16 cols [16*tj..16*tj+15].
// k/q double-buffered in LDS, 16 chunks of 32 cols, stride 36 words ->
// 4x ds_read_b128 at 36*(tj>>1)+16*(tj&1); conflict-free (R1-proven).
// Reductions: 4 DPP adds + 1 ds_swizzle xor16 (R3-proven). One barrier/step.
__global__ __launch_bounds__(256) void scan_kernel(
    const float* __restrict__ kbuf, const float* __restrict__ vbuf,
    const float* __restrict__ qbuf, float* __restrict__ out)
{
    __shared__ __align__(16) float ks[2][576];
    __shared__ __align__(16) float qs[2][576];
    __shared__ float vs[2][8];

    const int tid  = threadIdx.x;
    const int lane = tid & 63;
    const int tj   = lane & 31;
    const int b    = blockIdx.y;
    const int i0   = blockIdx.x * 8;
    const int r0   = tid >> 5;         // local row, one per 32-lane half

    // staging: thread writes logical cols {2tid, 2tid+1}: chunk=(2tid)>>5,
    // off=(2tid)&31 -> b64 write, conflict-free phases.
    const int wA = 36 * (tid >> 4) + ((2 * tid) & 31);
    // read: lane tj covers cols [16tj..16tj+15] = chunk tj>>1, half tj&1
    const int rA = 36 * (tj >> 1) + 16 * (tj & 1);

    f32x2 SA[8];
#pragma unroll
    for (int u = 0; u < 8; ++u) SA[u] = (f32x2)0.0f;

    float2 pk, pq; float pv = 0.0f;
    {   // stage t=0 into buf0; prefetch t=1 into regs
        const size_t o0 = (size_t)b * N_DIM;
        pk = *(const float2*)&kbuf[o0 + 2 * tid];
        pq = *(const float2*)&qbuf[o0 + 2 * tid];
        if (tid < 8) pv = vbuf[o0 + i0 + tid];
        *(float2*)&ks[0][wA] = pk;
        *(float2*)&qs[0][wA] = pq;
        if (tid < 8) vs[0][tid] = pv;
        const size_t o1 = (size_t)(B_DIM + b) * N_DIM;
        pk = *(const float2*)&kbuf[o1 + 2 * tid];
        pq = *(const float2*)&qbuf[o1 + 2 * tid];
        if (tid < 8) pv = vbuf[o1 + i0 + tid];
    }
    __syncthreads();

    const f32x2 Cv   = {C_FOLD, C_FOLD};
    const f32x2 M2Cv = {-2.0f * C_FOLD, -2.0f * C_FOLD};

    for (int t = 0; t < T_DIM; ++t) {
        const int cb = t & 1, nb = cb ^ 1;
        const size_t ofs = ((size_t)t * B_DIM + b) * N_DIM;

        // stage t+1 (already in regs) into the other buffer
        if (t + 1 < T_DIM) {
            *(float2*)&ks[nb][wA] = pk;
            *(float2*)&qs[nb][wA] = pq;
            if (tid < 8) vs[nb][tid] = pv;
        }
        // issue global prefetch for t+2
        if (t + 2 < T_DIM) {
            const size_t o2 = ((size_t)(t + 2) * B_DIM + b) * N_DIM;
            pk = *(const float2*)&kbuf[o2 + 2 * tid];
            pq = *(const float2*)&qbuf[o2 + 2 * tid];
            if (tid < 8) pv = vbuf[o2 + i0 + tid];
        }

        f32x2 k2[8], q2[8];
#pragma unroll
        for (int u = 0; u < 4; ++u) {
            f32x4 kv = *(const f32x4*)&ks[cb][rA + 4 * u];
            f32x4 qv = *(const f32x4*)&qs[cb][rA + 4 * u];
            k2[2*u] = kv.xy; k2[2*u+1] = kv.zw;
            q2[2*u] = qv.xy; q2[2*u+1] = qv.zw;
        }
        const float v0 = vs[cb][r0];

        // racc' = sum_j S'_ij k_j (2 partial accumulators for ILP)
        f32x2 pa = (f32x2)0.0f, pb = (f32x2)0.0f;
#pragma unroll
        for (int u = 0; u < 8; u += 2) {
            pa += SA[u]     * k2[u];
            pb += SA[u + 1] * k2[u + 1];
        }
        const float racc = half32_sum(pa.x + pa.y + pb.x + pb.y);

        const float dp = __builtin_fmaf(C_FOLD, v0, -racc);
        const f32x2 d0 = {dp, dp};

        // S'_new = C - 2C*rcp(exp2(S' + dp'*k)+1);  sq' += S'_new * q
        // 2 f32x2 chains per iter, fully unrolled -> compiler interleaves 8.
        f32x2 sa = (f32x2)0.0f, sb = (f32x2)0.0f;
#pragma unroll
        for (int u = 0; u < 8; u += 2) {
            f32x2 a0 = SA[u]     + d0 * k2[u];
            f32x2 a1 = SA[u + 1] + d0 * k2[u + 1];
            f32x2 e0 = { __builtin_amdgcn_exp2f(a0.x), __builtin_amdgcn_exp2f(a0.y) };
            f32x2 e1 = { __builtin_amdgcn_exp2f(a1.x), __builtin_amdgcn_exp2f(a1.y) };
            e0 = e0 + 1.0f; e1 = e1 + 1.0f;
            f32x2 rc0 = { __builtin_amdgcn_rcpf(e0.x), __builtin_amdgcn_rcpf(e0.y) };
            f32x2 rc1 = { __builtin_amdgcn_rcpf(e1.x), __builtin_amdgcn_rcpf(e1.y) };
            f32x2 n0 = Cv + rc0 * M2Cv;
            f32x2 n1 = Cv + rc1 * M2Cv;
            SA[u] = n0; SA[u + 1] = n1;
            sa += n0 * q2[u];
            sb += n1 * q2[u + 1];
        }
        const float sq = half32_sum(sa.x + sa.y + sb.x + sb.y);

        if (tj == 0) {
            float s0 = sq * INV_C;
            float g0 = __builtin_amdgcn_rcpf(1.0f + __builtin_amdgcn_exp2f(-s0 * 1.44269504f));
            out[ofs + i0 + r0] = s0 * s0 * g0;
        }
        __syncthreads();
    }

    // S_final (true scale) -> d_out[T*B*N + ((b*N + i)*N + col)]
    const size_t base = (size_t)T_DIM * B_DIM * N_DIM;
    const size_t so0 = base + ((size_t)b * N_DIM + i0 + r0) * N_DIM + 16 * tj;
#pragma unroll
    for (int u = 0; u < 4; ++u) {
        float4 w0;
        w0.x = SA[2*u].x   * INV_C; w0.y = SA[2*u].y   * INV_C;
        w0.z = SA[2*u+1].x * INV_C; w0.w = SA[2*u+1].y * INV_C;
        *(float4*)&out[so0 + 4 * u] = w0;
    }
}

extern "C" void kernel_launch(void* const* d_in, const int* in_sizes, int n_in,
                              void* d_out, int out_size, void* d_ws, size_t ws_size,
                              hipStream_t stream) {
    const float* x  = (const float*)d_in[0];
    const float* Wk = (const float*)d_in[1];
    const float* Wv = (const float*)d_in[2];
    const float* Wq = (const float*)d_in[3];
    float* outp = (float*)d_out;

    const size_t MN = (size_t)T_DIM * B_DIM * N_DIM;
    float* kbuf = (float*)d_ws;
    float* vbuf = kbuf + MN;
    float* qbuf = vbuf + MN;

    proj_gemm<<<dim3(128, 8, 3), 256, 0, stream>>>(x, Wk, Wv, Wq, kbuf, vbuf, qbuf);
    knorm<<<2048, 256, 0, stream>>>(kbuf);
    scan_kernel<<<dim3(64, 16), 256, 0, stream>>>(kbuf, vbuf, qbuf, outp);
}

// Round 2
// 800.408 us; speedup vs baseline: 1.0084x; 1.0084x over previous
//
#include <hip/hip_runtime.h>
#include <hip/hip_bf16.h>

#define T_DIM 512
#define B_DIM 16
#define D_DIM 1024
#define N_DIM 512

// c-fold: store S' = C*S so the exp2 argument is a single fma.
// C = 2*log2(e); tanh via exp2: tanh(x) = 1 - 2/(exp2(C*x)+1)
#define C_FOLD  2.885390082f
#define INV_C   0.3465735903f

typedef short s16x8 __attribute__((ext_vector_type(8)));
typedef float f32x4 __attribute__((ext_vector_type(4)));
typedef float f32x2 __attribute__((ext_vector_type(2)));

__device__ __forceinline__ unsigned short f2bf(float f) {
    unsigned u = __float_as_uint(f);
    unsigned r = (u + 0x7fffu + ((u >> 16) & 1u)) >> 16;
    return (unsigned short)r;
}

// sum over the 32 lanes of this half-wave, result broadcast to all 32.
// xor1/xor2 via quad_perm, xor4/xor8 via row_ror (VALU pipe), xor16 via one
// ds_swizzle. Proven in R3 (passed, 713us).
__device__ __forceinline__ float half32_sum(float x) {
    x += __int_as_float(__builtin_amdgcn_update_dpp(0, __float_as_int(x), 0xB1,  0xf, 0xf, true)); // quad_perm[1,0,3,2]
    x += __int_as_float(__builtin_amdgcn_update_dpp(0, __float_as_int(x), 0x4E,  0xf, 0xf, true)); // quad_perm[2,3,0,1]
    x += __int_as_float(__builtin_amdgcn_update_dpp(0, __float_as_int(x), 0x124, 0xf, 0xf, true)); // row_ror:4
    x += __int_as_float(__builtin_amdgcn_update_dpp(0, __float_as_int(x), 0x128, 0xf, 0xf, true)); // row_ror:8
    x += __int_as_float(__builtin_amdgcn_ds_swizzle(__float_as_int(x), 0x401F));                   // xor 16
    return x;
}

// ---------------- projection GEMM: C[m,n] = sum_d x[m,d] * W[n,d] ----------
__global__ __launch_bounds__(256) void proj_gemm(
    const float* __restrict__ x,
    const float* __restrict__ Wk,
    const float* __restrict__ Wv,
    const float* __restrict__ Wq,
    float* __restrict__ kbuf, float* __restrict__ vbuf, float* __restrict__ qbuf)
{
    const float* W = (blockIdx.z == 0) ? Wk : (blockIdx.z == 1) ? Wv : Wq;
    float* out = (blockIdx.z == 0) ? kbuf : (blockIdx.z == 1) ? vbuf : qbuf;

    __shared__ __align__(16) unsigned short As[64 * 40];
    __shared__ __align__(16) unsigned short Bs[64 * 40];

    const int tid  = threadIdx.x;
    const int m0   = blockIdx.x * 64;
    const int n0   = blockIdx.y * 64;
    const int wave = tid >> 6;
    const int lane = tid & 63;
    const int l15  = lane & 15;
    const int quad = lane >> 4;

    const int srow = tid >> 2;
    const int scol = (tid & 3) * 8;

    f32x4 acc[4];
#pragma unroll
    for (int i = 0; i < 4; ++i) acc[i] = (f32x4)0.0f;

    for (int k0 = 0; k0 < D_DIM; k0 += 32) {
        __syncthreads();
        {
            const float* srcA = &x[(size_t)(m0 + srow) * D_DIM + k0 + scol];
            float4 a0 = *(const float4*)srcA;
            float4 a1 = *(const float4*)(srcA + 4);
            uint4 pa;
            pa.x = (unsigned)f2bf(a0.x) | ((unsigned)f2bf(a0.y) << 16);
            pa.y = (unsigned)f2bf(a0.z) | ((unsigned)f2bf(a0.w) << 16);
            pa.z = (unsigned)f2bf(a1.x) | ((unsigned)f2bf(a1.y) << 16);
            pa.w = (unsigned)f2bf(a1.z) | ((unsigned)f2bf(a1.w) << 16);
            *(uint4*)&As[srow * 40 + scol] = pa;

            const float* srcB = &W[(size_t)(n0 + srow) * D_DIM + k0 + scol];
            float4 b0 = *(const float4*)srcB;
            float4 b1 = *(const float4*)(srcB + 4);
            uint4 pb;
            pb.x = (unsigned)f2bf(b0.x) | ((unsigned)f2bf(b0.y) << 16);
            pb.y = (unsigned)f2bf(b0.z) | ((unsigned)f2bf(b0.w) << 16);
            pb.z = (unsigned)f2bf(b1.x) | ((unsigned)f2bf(b1.y) << 16);
            pb.w = (unsigned)f2bf(b1.z) | ((unsigned)f2bf(b1.w) << 16);
            *(uint4*)&Bs[srow * 40 + scol] = pb;
        }
        __syncthreads();
        s16x8 af = *(const s16x8*)&As[(wave * 16 + l15) * 40 + quad * 8];
#pragma unroll
        for (int nt = 0; nt < 4; ++nt) {
            s16x8 bf = *(const s16x8*)&Bs[(nt * 16 + l15) * 40 + quad * 8];
            acc[nt] = __builtin_amdgcn_mfma_f32_16x16x32_bf16(af, bf, acc[nt], 0, 0, 0);
        }
    }
#pragma unroll
    for (int nt = 0; nt < 4; ++nt) {
#pragma unroll
        for (int rg = 0; rg < 4; ++rg) {
            int row = m0 + wave * 16 + quad * 4 + rg;
            int col = n0 + nt * 16 + l15;
            out[(size_t)row * N_DIM + col] = acc[nt][rg];
        }
    }
}

// ---------------- k row-normalization (in place) ---------------------------
__global__ __launch_bounds__(256) void knorm(float* __restrict__ kbuf)
{
    const int wave = threadIdx.x >> 6;
    const int lane = threadIdx.x & 63;
    const int row  = blockIdx.x * 4 + wave;
    float* p = &kbuf[(size_t)row * N_DIM + lane * 8];
    float4 a = *(const float4*)p;
    float4 b = *(const float4*)(p + 4);
    float s = a.x*a.x + a.y*a.y + a.z*a.z + a.w*a.w
            + b.x*b.x + b.y*b.y + b.z*b.z + b.w*b.w;
#pragma unroll
    for (int m = 1; m < 64; m <<= 1) s += __shfl_xor(s, m, 64);
    float inv = 1.0f / (sqrtf(s) + 1e-6f);
    a.x *= inv; a.y *= inv; a.z *= inv; a.w *= inv;
    b.x *= inv; b.y *= inv; b.z *= inv; b.w *= inv;
    *(float4*)p = a;
    *(float4*)(p + 4) = b;
}

// ---------------- sequential scan ------------------------------------------
// grid(32, 16): x = 16-row chunk, y = batch. block 256 (4 waves).
// R5: WAVE-PRIVATE k/q staging -> ZERO barriers in the 512-step loop.
// R4 post-mortem: occupancy 2x (19.9->35.3%) did NOT raise VALUBusy (73.9->71.9)
// and time regressed -> the ~28% idle is the per-step __syncthreads convoy
// (all waves of a block wait on the slowest wave's serial chain), which extra
// waves cannot fill. Each lane only touches k/q cols [16tj,16tj+16), so a wave
// collectively needs exactly one full row: each wave now loads the full k/q row
// itself (2 extra dwordx4 per array per step) and stages into its own LDS
// double-buffer. Writer == reader wave -> in-wave lgkmcnt ordering suffices,
// no __syncthreads, waves free-run and hide each other's chain stalls.
// Layout/reductions unchanged (R1 conflict-free stride-36, R3 DPP+swizzle).
// v is read per-lane from global (broadcast load) with a 2-step reg rotation.
// LDS: 4 waves x 2 buf x (576+576) floats = 36.9 KB/block (2 blocks/CU ok).
__global__ __launch_bounds__(256) void scan_kernel(
    const float* __restrict__ kbuf, const float* __restrict__ vbuf,
    const float* __restrict__ qbuf, float* __restrict__ out)
{
    __shared__ __align__(16) float ks[4][2][576];
    __shared__ __align__(16) float qs[4][2][576];

    const int tid  = threadIdx.x;
    const int lane = tid & 63;
    const int wv   = tid >> 6;
    const int h    = lane >> 5;
    const int tj   = lane & 31;
    const int b    = blockIdx.y;
    const int i0   = blockIdx.x * 16;
    const int r0   = 4 * wv + 2 * h;   // local rows r0, r0+1

    // wave-private staging: lane writes cols [8*lane, 8*lane+8) as 2x b128.
    // col c lives at word 36*(c>>5) + (c&31); 8*lane & 31 in {0,8,16,24} so
    // each b128 is contiguous & 16B-aligned; 8-lane phases hit 32 distinct
    // banks (same stride-36 math as the R1-proven pattern).
    const int wA = 36 * (lane >> 2) + ((8 * lane) & 31);
    // read: lane tj covers cols [16tj..16tj+15] = chunk tj>>1, half tj&1
    const int rA = 36 * (tj >> 1) + 16 * (tj & 1);

    f32x2 SA[8], SB[8];
#pragma unroll
    for (int u = 0; u < 8; ++u) { SA[u] = (f32x2)0.0f; SB[u] = (f32x2)0.0f; }

    float4 pka, pkb, pqa, pqb;          // k/q row for t+2 (in flight)
    float va0, va1, vb0, vb1;           // v for t (va) and t+1 (vb)
    {   // stage t=0 into buf0; prefetch t=1 into regs
        const size_t o0 = (size_t)b * N_DIM + 8 * lane;
        pka = *(const float4*)&kbuf[o0];
        pkb = *(const float4*)&kbuf[o0 + 4];
        pqa = *(const float4*)&qbuf[o0];
        pqb = *(const float4*)&qbuf[o0 + 4];
        *(float4*)&ks[wv][0][wA]     = pka;
        *(float4*)&ks[wv][0][wA + 4] = pkb;
        *(float4*)&qs[wv][0][wA]     = pqa;
        *(float4*)&qs[wv][0][wA + 4] = pqb;
        const size_t o1 = ((size_t)B_DIM + b) * N_DIM + 8 * lane;
        pka = *(const float4*)&kbuf[o1];
        pkb = *(const float4*)&kbuf[o1 + 4];
        pqa = *(const float4*)&qbuf[o1];
        pqb = *(const float4*)&qbuf[o1 + 4];
        const size_t v0o = (size_t)b * N_DIM + i0 + r0;
        const size_t v1o = ((size_t)B_DIM + b) * N_DIM + i0 + r0;
        va0 = vbuf[v0o]; va1 = vbuf[v0o + 1];
        vb0 = vbuf[v1o]; vb1 = vbuf[v1o + 1];
    }

    const f32x2 Cv   = {C_FOLD, C_FOLD};
    const f32x2 M2Cv = {-2.0f * C_FOLD, -2.0f * C_FOLD};

    for (int t = 0; t < T_DIM; ++t) {
        const int cb = t & 1, nb = cb ^ 1;
        const size_t ofs = ((size_t)t * B_DIM + b) * N_DIM;

        // stage t+1 (already in regs) into the other (wave-private) buffer
        if (t + 1 < T_DIM) {
            *(float4*)&ks[wv][nb][wA]     = pka;
            *(float4*)&ks[wv][nb][wA + 4] = pkb;
            *(float4*)&qs[wv][nb][wA]     = pqa;
            *(float4*)&qs[wv][nb][wA + 4] = pqb;
        }
        // issue global prefetch for t+2
        float vt0 = 0.0f, vt1 = 0.0f;
        if (t + 2 < T_DIM) {
            const size_t o2 = ((size_t)(t + 2) * B_DIM + b) * N_DIM;
            pka = *(const float4*)&kbuf[o2 + 8 * lane];
            pkb = *(const float4*)&kbuf[o2 + 8 * lane + 4];
            pqa = *(const float4*)&qbuf[o2 + 8 * lane];
            pqb = *(const float4*)&qbuf[o2 + 8 * lane + 4];
            vt0 = vbuf[o2 + i0 + r0];
            vt1 = vbuf[o2 + i0 + r0 + 1];
        }

        f32x2 k2[8], q2[8];
#pragma unroll
        for (int u = 0; u < 4; ++u) {
            f32x4 kv = *(const f32x4*)&ks[wv][cb][rA + 4 * u];
            f32x4 qv = *(const f32x4*)&qs[wv][cb][rA + 4 * u];
            k2[2*u] = kv.xy; k2[2*u+1] = kv.zw;
            q2[2*u] = qv.xy; q2[2*u+1] = qv.zw;
        }
        const float v0 = va0;
        const float v1 = va1;

        // racc' = sum_j S'_ij k_j (2 partial accumulators per row)
        f32x2 pa0 = (f32x2)0.0f, pb0 = (f32x2)0.0f;
        f32x2 pa1 = (f32x2)0.0f, pb1 = (f32x2)0.0f;
#pragma unroll
        for (int u = 0; u < 8; u += 2) {
            pa0 += SA[u] * k2[u];  pb0 += SA[u + 1] * k2[u + 1];
            pa1 += SB[u] * k2[u];  pb1 += SB[u + 1] * k2[u + 1];
        }
        const float racc0 = half32_sum(pa0.x + pa0.y + pb0.x + pb0.y);
        const float racc1 = half32_sum(pa1.x + pa1.y + pb1.x + pb1.y);

        const float dp0 = __builtin_fmaf(C_FOLD, v0, -racc0);
        const float dp1 = __builtin_fmaf(C_FOLD, v1, -racc1);
        const f32x2 d0 = {dp0, dp0}, d1 = {dp1, dp1};

        // S'_new = C - 2C*rcp(exp2(S' + dp'*k)+1);  sq' += S'_new * q
        // 4 chains interleaved (SA/SB x u/u+1) for ILP.
        f32x2 sa0 = (f32x2)0.0f, sb0 = (f32x2)0.0f;
        f32x2 sa1 = (f32x2)0.0f, sb1 = (f32x2)0.0f;
#pragma unroll
        for (int u = 0; u < 8; u += 2) {
            f32x2 aA0 = SA[u]     + d0 * k2[u];
            f32x2 aB0 = SB[u]     + d1 * k2[u];
            f32x2 aA1 = SA[u + 1] + d0 * k2[u + 1];
            f32x2 aB1 = SB[u + 1] + d1 * k2[u + 1];
            f32x2 eA0 = { __builtin_amdgcn_exp2f(aA0.x), __builtin_amdgcn_exp2f(aA0.y) };
            f32x2 eB0 = { __builtin_amdgcn_exp2f(aB0.x), __builtin_amdgcn_exp2f(aB0.y) };
            f32x2 eA1 = { __builtin_amdgcn_exp2f(aA1.x), __builtin_amdgcn_exp2f(aA1.y) };
            f32x2 eB1 = { __builtin_amdgcn_exp2f(aB1.x), __builtin_amdgcn_exp2f(aB1.y) };
            eA0 = eA0 + 1.0f; eB0 = eB0 + 1.0f; eA1 = eA1 + 1.0f; eB1 = eB1 + 1.0f;
            f32x2 rA0 = { __builtin_amdgcn_rcpf(eA0.x), __builtin_amdgcn_rcpf(eA0.y) };
            f32x2 rB0 = { __builtin_amdgcn_rcpf(eB0.x), __builtin_amdgcn_rcpf(eB0.y) };
            f32x2 rA1 = { __builtin_amdgcn_rcpf(eA1.x), __builtin_amdgcn_rcpf(eA1.y) };
            f32x2 rB1 = { __builtin_amdgcn_rcpf(eB1.x), __builtin_amdgcn_rcpf(eB1.y) };
            f32x2 nA0 = Cv + rA0 * M2Cv;
            f32x2 nB0 = Cv + rB0 * M2Cv;
            f32x2 nA1 = Cv + rA1 * M2Cv;
            f32x2 nB1 = Cv + rB1 * M2Cv;
            SA[u] = nA0; SB[u] = nB0; SA[u + 1] = nA1; SB[u + 1] = nB1;
            sa0 += nA0 * q2[u];     sa1 += nB0 * q2[u];
            sb0 += nA1 * q2[u + 1]; sb1 += nB1 * q2[u + 1];
        }
        const float sq0 = half32_sum(sa0.x + sa0.y + sb0.x + sb0.y);
        const float sq1 = half32_sum(sa1.x + sa1.y + sb1.x + sb1.y);

        if (tj == 0) {
            float s0 = sq0 * INV_C, s1 = sq1 * INV_C;
            float g0 = __builtin_amdgcn_rcpf(1.0f + __builtin_amdgcn_exp2f(-s0 * 1.44269504f));
            float g1 = __builtin_amdgcn_rcpf(1.0f + __builtin_amdgcn_exp2f(-s1 * 1.44269504f));
            out[ofs + i0 + r0]     = s0 * s0 * g0;
            out[ofs + i0 + r0 + 1] = s1 * s1 * g1;
        }

        va0 = vb0; va1 = vb1; vb0 = vt0; vb1 = vt1;
    }

    // S_final (true scale) -> d_out[T*B*N + ((b*N + i)*N + col)]
    const size_t base = (size_t)T_DIM * B_DIM * N_DIM;
    const size_t so0 = base + ((size_t)b * N_DIM + i0 + r0) * N_DIM + 16 * tj;
    const size_t so1 = so0 + N_DIM;
#pragma unroll
    for (int u = 0; u < 4; ++u) {
        float4 w0, w1;
        w0.x = SA[2*u].x   * INV_C; w0.y = SA[2*u].y   * INV_C;
        w0.z = SA[2*u+1].x * INV_C; w0.w = SA[2*u+1].y * INV_C;
        w1.x = SB[2*u].x   * INV_C; w1.y = SB[2*u].y   * INV_C;
        w1.z = SB[2*u+1].x * INV_C; w1.w = SB[2*u+1].y * INV_C;
        *(float4*)&out[so0 + 4 * u] = w0;
        *(float4*)&out[so1 + 4 * u] = w1;
    }
}

extern "C" void kernel_launch(void* const* d_in, const int* in_sizes, int n_in,
                              void* d_out, int out_size, void* d_ws, size_t ws_size,
                              hipStream_t stream) {
    const float* x  = (const float*)d_in[0];
    const float* Wk = (const float*)d_in[1];
    const float* Wv = (const float*)d_in[2];
    const float* Wq = (const float*)d_in[3];
    float* outp = (float*)d_out;

    const size_t MN = (size_t)T_DIM * B_DIM * N_DIM;
    float* kbuf = (float*)d_ws;
    float* vbuf = kbuf + MN;
    float* qbuf = vbuf + MN;

    proj_gemm<<<dim3(128, 8, 3), 256, 0, stream>>>(x, Wk, Wv, Wq, kbuf, vbuf, qbuf);
    knorm<<<2048, 256, 0, stream>>>(kbuf);
    scan_kernel<<<dim3(32, 16), 256, 0, stream>>>(kbuf, vbuf, qbuf, outp);
}

// Round 3
// 765.987 us; speedup vs baseline: 1.0537x; 1.0449x over previous
//
#include <hip/hip_runtime.h>
#include <hip/hip_bf16.h>

#define T_DIM 512
#define B_DIM 16
#define D_DIM 1024
#define N_DIM 512

// c-fold: store S' = C*S so the exp2 argument is a single fma.
// C = 2*log2(e); tanh via exp2: tanh(x) = 1 - 2/(exp2(C*x)+1)
#define C_FOLD  2.885390082f
#define INV_C   0.3465735903f

typedef short s16x8 __attribute__((ext_vector_type(8)));
typedef float f32x4 __attribute__((ext_vector_type(4)));
typedef float f32x2 __attribute__((ext_vector_type(2)));

__device__ __forceinline__ unsigned short f2bf(float f) {
    unsigned u = __float_as_uint(f);
    unsigned r = (u + 0x7fffu + ((u >> 16) & 1u)) >> 16;
    return (unsigned short)r;
}

// sum over the 32 lanes of this half-wave, result broadcast to all 32.
// xor1/xor2 via quad_perm, xor4/xor8 via row_ror (VALU pipe), xor16 via one
// ds_swizzle. Proven in R3 (passed, 713us).
__device__ __forceinline__ float half32_sum(float x) {
    x += __int_as_float(__builtin_amdgcn_update_dpp(0, __float_as_int(x), 0xB1,  0xf, 0xf, true)); // quad_perm[1,0,3,2]
    x += __int_as_float(__builtin_amdgcn_update_dpp(0, __float_as_int(x), 0x4E,  0xf, 0xf, true)); // quad_perm[2,3,0,1]
    x += __int_as_float(__builtin_amdgcn_update_dpp(0, __float_as_int(x), 0x124, 0xf, 0xf, true)); // row_ror:4
    x += __int_as_float(__builtin_amdgcn_update_dpp(0, __float_as_int(x), 0x128, 0xf, 0xf, true)); // row_ror:8
    x += __int_as_float(__builtin_amdgcn_ds_swizzle(__float_as_int(x), 0x401F));                   // xor 16
    return x;
}

// ---------------- projection GEMM: C[m,n] = sum_d x[m,d] * W[n,d] ----------
__global__ __launch_bounds__(256) void proj_gemm(
    const float* __restrict__ x,
    const float* __restrict__ Wk,
    const float* __restrict__ Wv,
    const float* __restrict__ Wq,
    float* __restrict__ kbuf, float* __restrict__ vbuf, float* __restrict__ qbuf)
{
    const float* W = (blockIdx.z == 0) ? Wk : (blockIdx.z == 1) ? Wv : Wq;
    float* out = (blockIdx.z == 0) ? kbuf : (blockIdx.z == 1) ? vbuf : qbuf;

    __shared__ __align__(16) unsigned short As[64 * 40];
    __shared__ __align__(16) unsigned short Bs[64 * 40];

    const int tid  = threadIdx.x;
    const int m0   = blockIdx.x * 64;
    const int n0   = blockIdx.y * 64;
    const int wave = tid >> 6;
    const int lane = tid & 63;
    const int l15  = lane & 15;
    const int quad = lane >> 4;

    const int srow = tid >> 2;
    const int scol = (tid & 3) * 8;

    f32x4 acc[4];
#pragma unroll
    for (int i = 0; i < 4; ++i) acc[i] = (f32x4)0.0f;

    for (int k0 = 0; k0 < D_DIM; k0 += 32) {
        __syncthreads();
        {
            const float* srcA = &x[(size_t)(m0 + srow) * D_DIM + k0 + scol];
            float4 a0 = *(const float4*)srcA;
            float4 a1 = *(const float4*)(srcA + 4);
            uint4 pa;
            pa.x = (unsigned)f2bf(a0.x) | ((unsigned)f2bf(a0.y) << 16);
            pa.y = (unsigned)f2bf(a0.z) | ((unsigned)f2bf(a0.w) << 16);
            pa.z = (unsigned)f2bf(a1.x) | ((unsigned)f2bf(a1.y) << 16);
            pa.w = (unsigned)f2bf(a1.z) | ((unsigned)f2bf(a1.w) << 16);
            *(uint4*)&As[srow * 40 + scol] = pa;

            const float* srcB = &W[(size_t)(n0 + srow) * D_DIM + k0 + scol];
            float4 b0 = *(const float4*)srcB;
            float4 b1 = *(const float4*)(srcB + 4);
            uint4 pb;
            pb.x = (unsigned)f2bf(b0.x) | ((unsigned)f2bf(b0.y) << 16);
            pb.y = (unsigned)f2bf(b0.z) | ((unsigned)f2bf(b0.w) << 16);
            pb.z = (unsigned)f2bf(b1.x) | ((unsigned)f2bf(b1.y) << 16);
            pb.w = (unsigned)f2bf(b1.z) | ((unsigned)f2bf(b1.w) << 16);
            *(uint4*)&Bs[srow * 40 + scol] = pb;
        }
        __syncthreads();
        s16x8 af = *(const s16x8*)&As[(wave * 16 + l15) * 40 + quad * 8];
#pragma unroll
        for (int nt = 0; nt < 4; ++nt) {
            s16x8 bf = *(const s16x8*)&Bs[(nt * 16 + l15) * 40 + quad * 8];
            acc[nt] = __builtin_amdgcn_mfma_f32_16x16x32_bf16(af, bf, acc[nt], 0, 0, 0);
        }
    }
#pragma unroll
    for (int nt = 0; nt < 4; ++nt) {
#pragma unroll
        for (int rg = 0; rg < 4; ++rg) {
            int row = m0 + wave * 16 + quad * 4 + rg;
            int col = n0 + nt * 16 + l15;
            out[(size_t)row * N_DIM + col] = acc[nt][rg];
        }
    }
}

// ---------------- k row-normalization (in place) ---------------------------
__global__ __launch_bounds__(256) void knorm(float* __restrict__ kbuf)
{
    const int wave = threadIdx.x >> 6;
    const int lane = threadIdx.x & 63;
    const int row  = blockIdx.x * 4 + wave;
    float* p = &kbuf[(size_t)row * N_DIM + lane * 8];
    float4 a = *(const float4*)p;
    float4 b = *(const float4*)(p + 4);
    float s = a.x*a.x + a.y*a.y + a.z*a.z + a.w*a.w
            + b.x*b.x + b.y*b.y + b.z*b.z + b.w*b.w;
#pragma unroll
    for (int m = 1; m < 64; m <<= 1) s += __shfl_xor(s, m, 64);
    float inv = 1.0f / (sqrtf(s) + 1e-6f);
    a.x *= inv; a.y *= inv; a.z *= inv; a.w *= inv;
    b.x *= inv; b.y *= inv; b.z *= inv; b.w *= inv;
    *(float4*)p = a;
    *(float4*)(p + 4) = b;
}

// ---------------- sequential scan ------------------------------------------
// grid(32, 16): x = 16-row chunk, y = batch. block 256.
// Structure = R3 (block staging + 1 barrier/step; R4 proved extra waves don't
// help, R5 proved removing barriers doesn't help -> pipe-throughput-bound).
// R6: GROUPED RECIPROCAL. Per-step pipe-busy is dominated by 64 quarter-rate
// trans ops/thread (32 exp2 + 32 rcp = 512 cyc of ~830). The 8 rcps of one
// unroll iter are replaced by rcp(product) + prefix/suffix recovery:
// 10 packed muls + 1 scalar mul + 1 v_rcp (~30 cyc) instead of 8 v_rcp
// (64 cyc). Range-safe: f=e+1 in [1,~33], prod of 8 <= ~1.4e12 << f32 max;
// rel err ~1e-6. Trans/thread: 64 -> 36 (-144 cyc/step predicted).
__global__ __launch_bounds__(256) void scan_kernel(
    const float* __restrict__ kbuf, const float* __restrict__ vbuf,
    const float* __restrict__ qbuf, float* __restrict__ out)
{
    __shared__ __align__(16) float ks[2][576];
    __shared__ __align__(16) float qs[2][576];
    __shared__ float vs[2][16];

    const int tid  = threadIdx.x;
    const int lane = tid & 63;
    const int wv   = tid >> 6;
    const int h    = lane >> 5;
    const int tj   = lane & 31;
    const int b    = blockIdx.y;
    const int i0   = blockIdx.x * 16;
    const int r0   = 4 * wv + 2 * h;   // local rows r0, r0+1

    // staging: thread writes logical cols {2tid, 2tid+1}: chunk=(2tid)>>5,
    // off=(2tid)&31 -> b64 write, conflict-free phases.
    const int wA = 36 * (tid >> 4) + ((2 * tid) & 31);
    // read: lane tj covers cols [16tj..16tj+15] = chunk tj>>1, half tj&1
    const int rA = 36 * (tj >> 1) + 16 * (tj & 1);

    f32x2 SA[8], SB[8];
#pragma unroll
    for (int u = 0; u < 8; ++u) { SA[u] = (f32x2)0.0f; SB[u] = (f32x2)0.0f; }

    float2 pk, pq; float pv = 0.0f;
    {   // stage t=0 into buf0; prefetch t=1 into regs
        const size_t o0 = (size_t)b * N_DIM;
        pk = *(const float2*)&kbuf[o0 + 2 * tid];
        pq = *(const float2*)&qbuf[o0 + 2 * tid];
        if (tid < 16) pv = vbuf[o0 + i0 + tid];
        *(float2*)&ks[0][wA] = pk;
        *(float2*)&qs[0][wA] = pq;
        if (tid < 16) vs[0][tid] = pv;
        const size_t o1 = (size_t)(B_DIM + b) * N_DIM;
        pk = *(const float2*)&kbuf[o1 + 2 * tid];
        pq = *(const float2*)&qbuf[o1 + 2 * tid];
        if (tid < 16) pv = vbuf[o1 + i0 + tid];
    }
    __syncthreads();

    const f32x2 Cv   = {C_FOLD, C_FOLD};
    const f32x2 M2Cv = {-2.0f * C_FOLD, -2.0f * C_FOLD};

    for (int t = 0; t < T_DIM; ++t) {
        const int cb = t & 1, nb = cb ^ 1;
        const size_t ofs = ((size_t)t * B_DIM + b) * N_DIM;

        // stage t+1 (already in regs) into the other buffer
        if (t + 1 < T_DIM) {
            *(float2*)&ks[nb][wA] = pk;
            *(float2*)&qs[nb][wA] = pq;
            if (tid < 16) vs[nb][tid] = pv;
        }
        // issue global prefetch for t+2
        if (t + 2 < T_DIM) {
            const size_t o2 = ((size_t)(t + 2) * B_DIM + b) * N_DIM;
            pk = *(const float2*)&kbuf[o2 + 2 * tid];
            pq = *(const float2*)&qbuf[o2 + 2 * tid];
            if (tid < 16) pv = vbuf[o2 + i0 + tid];
        }

        f32x2 k2[8], q2[8];
#pragma unroll
        for (int u = 0; u < 4; ++u) {
            f32x4 kv = *(const f32x4*)&ks[cb][rA + 4 * u];
            f32x4 qv = *(const f32x4*)&qs[cb][rA + 4 * u];
            k2[2*u] = kv.xy; k2[2*u+1] = kv.zw;
            q2[2*u] = qv.xy; q2[2*u+1] = qv.zw;
        }
        const float v0 = vs[cb][r0];
        const float v1 = vs[cb][r0 + 1];

        // racc' = sum_j S'_ij k_j (2 partial accumulators per row)
        f32x2 pa0 = (f32x2)0.0f, pb0 = (f32x2)0.0f;
        f32x2 pa1 = (f32x2)0.0f, pb1 = (f32x2)0.0f;
#pragma unroll
        for (int u = 0; u < 8; u += 2) {
            pa0 += SA[u] * k2[u];  pb0 += SA[u + 1] * k2[u + 1];
            pa1 += SB[u] * k2[u];  pb1 += SB[u + 1] * k2[u + 1];
        }
        const float racc0 = half32_sum(pa0.x + pa0.y + pb0.x + pb0.y);
        const float racc1 = half32_sum(pa1.x + pa1.y + pb1.x + pb1.y);

        const float dp0 = __builtin_fmaf(C_FOLD, v0, -racc0);
        const float dp1 = __builtin_fmaf(C_FOLD, v1, -racc1);
        const f32x2 d0 = {dp0, dp0}, d1 = {dp1, dp1};

        // S'_new = C - 2C/(exp2(S' + dp'*k)+1);  sq' += S'_new * q
        // Grouped rcp: one v_rcp per 8 elems, individuals recovered via
        // prefix/suffix products (4 independent group-chains interleave).
        f32x2 sa0 = (f32x2)0.0f, sb0 = (f32x2)0.0f;
        f32x2 sa1 = (f32x2)0.0f, sb1 = (f32x2)0.0f;
#pragma unroll
        for (int u = 0; u < 8; u += 2) {
            f32x2 aA0 = SA[u]     + d0 * k2[u];
            f32x2 aB0 = SB[u]     + d1 * k2[u];
            f32x2 aA1 = SA[u + 1] + d0 * k2[u + 1];
            f32x2 aB1 = SB[u + 1] + d1 * k2[u + 1];
            f32x2 fA0 = { __builtin_amdgcn_exp2f(aA0.x), __builtin_amdgcn_exp2f(aA0.y) };
            f32x2 fB0 = { __builtin_amdgcn_exp2f(aB0.x), __builtin_amdgcn_exp2f(aB0.y) };
            f32x2 fA1 = { __builtin_amdgcn_exp2f(aA1.x), __builtin_amdgcn_exp2f(aA1.y) };
            f32x2 fB1 = { __builtin_amdgcn_exp2f(aB1.x), __builtin_amdgcn_exp2f(aB1.y) };
            fA0 = fA0 + 1.0f; fB0 = fB0 + 1.0f; fA1 = fA1 + 1.0f; fB1 = fB1 + 1.0f;
            // product tree over the 8 scalars {fA0,fB0,fA1,fB1}.{x,y}
            f32x2 m0 = fA0 * fB0;
            f32x2 m1 = fA1 * fB1;
            f32x2 qq = m0 * m1;
            float rP = __builtin_amdgcn_rcpf(qq.x * qq.y);
            f32x2 rq  = { qq.y * rP, qq.x * rP };   // {1/qq.x, 1/qq.y}
            f32x2 rm0 = rq * m1;                     // {1/m0.x, 1/m0.y}
            f32x2 rm1 = rq * m0;                     // {1/m1.x, 1/m1.y}
            f32x2 rA0 = rm0 * fB0;                   // 1/fA0
            f32x2 rB0 = rm0 * fA0;                   // 1/fB0
            f32x2 rA1 = rm1 * fB1;                   // 1/fA1
            f32x2 rB1 = rm1 * fA1;                   // 1/fB1
            f32x2 nA0 = Cv + rA0 * M2Cv;
            f32x2 nB0 = Cv + rB0 * M2Cv;
            f32x2 nA1 = Cv + rA1 * M2Cv;
            f32x2 nB1 = Cv + rB1 * M2Cv;
            SA[u] = nA0; SB[u] = nB0; SA[u + 1] = nA1; SB[u + 1] = nB1;
            sa0 += nA0 * q2[u];     sa1 += nB0 * q2[u];
            sb0 += nA1 * q2[u + 1]; sb1 += nB1 * q2[u + 1];
        }
        const float sq0 = half32_sum(sa0.x + sa0.y + sb0.x + sb0.y);
        const float sq1 = half32_sum(sa1.x + sa1.y + sb1.x + sb1.y);

        if (tj == 0) {
            float s0 = sq0 * INV_C, s1 = sq1 * INV_C;
            float g0 = __builtin_amdgcn_rcpf(1.0f + __builtin_amdgcn_exp2f(-s0 * 1.44269504f));
            float g1 = __builtin_amdgcn_rcpf(1.0f + __builtin_amdgcn_exp2f(-s1 * 1.44269504f));
            out[ofs + i0 + r0]     = s0 * s0 * g0;
            out[ofs + i0 + r0 + 1] = s1 * s1 * g1;
        }
        __syncthreads();
    }

    // S_final (true scale) -> d_out[T*B*N + ((b*N + i)*N + col)]
    const size_t base = (size_t)T_DIM * B_DIM * N_DIM;
    const size_t so0 = base + ((size_t)b * N_DIM + i0 + r0) * N_DIM + 16 * tj;
    const size_t so1 = so0 + N_DIM;
#pragma unroll
    for (int u = 0; u < 4; ++u) {
        float4 w0, w1;
        w0.x = SA[2*u].x   * INV_C; w0.y = SA[2*u].y   * INV_C;
        w0.z = SA[2*u+1].x * INV_C; w0.w = SA[2*u+1].y * INV_C;
        w1.x = SB[2*u].x   * INV_C; w1.y = SB[2*u].y   * INV_C;
        w1.z = SB[2*u+1].x * INV_C; w1.w = SB[2*u+1].y * INV_C;
        *(float4*)&out[so0 + 4 * u] = w0;
        *(float4*)&out[so1 + 4 * u] = w1;
    }
}

extern "C" void kernel_launch(void* const* d_in, const int* in_sizes, int n_in,
                              void* d_out, int out_size, void* d_ws, size_t ws_size,
                              hipStream_t stream) {
    const float* x  = (const float*)d_in[0];
    const float* Wk = (const float*)d_in[1];
    const float* Wv = (const float*)d_in[2];
    const float* Wq = (const float*)d_in[3];
    float* outp = (float*)d_out;

    const size_t MN = (size_t)T_DIM * B_DIM * N_DIM;
    float* kbuf = (float*)d_ws;
    float* vbuf = kbuf + MN;
    float* qbuf = vbuf + MN;

    proj_gemm<<<dim3(128, 8, 3), 256, 0, stream>>>(x, Wk, Wv, Wq, kbuf, vbuf, qbuf);
    knorm<<<2048, 256, 0, stream>>>(kbuf);
    scan_kernel<<<dim3(32, 16), 256, 0, stream>>>(kbuf, vbuf, qbuf, outp);
}

// Round 4
// 704.875 us; speedup vs baseline: 1.1451x; 1.0867x over previous
//
#include <hip/hip_runtime.h>
#include <hip/hip_bf16.h>

#define T_DIM 512
#define B_DIM 16
#define D_DIM 1024
#define N_DIM 512

// c-fold: store S' = C*S so the exp2 argument is a single fma.
// C = 2*log2(e); tanh via exp2: tanh(x) = 1 - 2/(exp2(C*x)+1)
#define C_FOLD  2.885390082f
#define INV_C   0.3465735903f

typedef short s16x8 __attribute__((ext_vector_type(8)));
typedef float f32x4 __attribute__((ext_vector_type(4)));
typedef float f32x2 __attribute__((ext_vector_type(2)));

__device__ __forceinline__ unsigned short f2bf(float f) {
    unsigned u = __float_as_uint(f);
    unsigned r = (u + 0x7fffu + ((u >> 16) & 1u)) >> 16;
    return (unsigned short)r;
}

// sum over the 16 lanes of this DPP row, result broadcast to all 16.
// This is the proven half32_sum (R3) minus its final ds_swizzle xor16:
// xor1/xor2 via quad_perm, then ror4+ror8 complete the 16-lane all-reduce.
// Pure VALU pipe - NO LDS round trip.
__device__ __forceinline__ float reduce16(float x) {
    x += __int_as_float(__builtin_amdgcn_update_dpp(0, __float_as_int(x), 0xB1,  0xf, 0xf, true)); // quad_perm[1,0,3,2]
    x += __int_as_float(__builtin_amdgcn_update_dpp(0, __float_as_int(x), 0x4E,  0xf, 0xf, true)); // quad_perm[2,3,0,1]
    x += __int_as_float(__builtin_amdgcn_update_dpp(0, __float_as_int(x), 0x124, 0xf, 0xf, true)); // row_ror:4
    x += __int_as_float(__builtin_amdgcn_update_dpp(0, __float_as_int(x), 0x128, 0xf, 0xf, true)); // row_ror:8
    return x;
}

// ---------------- projection GEMM: C[m,n] = sum_d x[m,d] * W[n,d] ----------
__global__ __launch_bounds__(256) void proj_gemm(
    const float* __restrict__ x,
    const float* __restrict__ Wk,
    const float* __restrict__ Wv,
    const float* __restrict__ Wq,
    float* __restrict__ kbuf, float* __restrict__ vbuf, float* __restrict__ qbuf)
{
    const float* W = (blockIdx.z == 0) ? Wk : (blockIdx.z == 1) ? Wv : Wq;
    float* out = (blockIdx.z == 0) ? kbuf : (blockIdx.z == 1) ? vbuf : qbuf;

    __shared__ __align__(16) unsigned short As[64 * 40];
    __shared__ __align__(16) unsigned short Bs[64 * 40];

    const int tid  = threadIdx.x;
    const int m0   = blockIdx.x * 64;
    const int n0   = blockIdx.y * 64;
    const int wave = tid >> 6;
    const int lane = tid & 63;
    const int l15  = lane & 15;
    const int quad = lane >> 4;

    const int srow = tid >> 2;
    const int scol = (tid & 3) * 8;

    f32x4 acc[4];
#pragma unroll
    for (int i = 0; i < 4; ++i) acc[i] = (f32x4)0.0f;

    for (int k0 = 0; k0 < D_DIM; k0 += 32) {
        __syncthreads();
        {
            const float* srcA = &x[(size_t)(m0 + srow) * D_DIM + k0 + scol];
            float4 a0 = *(const float4*)srcA;
            float4 a1 = *(const float4*)(srcA + 4);
            uint4 pa;
            pa.x = (unsigned)f2bf(a0.x) | ((unsigned)f2bf(a0.y) << 16);
            pa.y = (unsigned)f2bf(a0.z) | ((unsigned)f2bf(a0.w) << 16);
            pa.z = (unsigned)f2bf(a1.x) | ((unsigned)f2bf(a1.y) << 16);
            pa.w = (unsigned)f2bf(a1.z) | ((unsigned)f2bf(a1.w) << 16);
            *(uint4*)&As[srow * 40 + scol] = pa;

            const float* srcB = &W[(size_t)(n0 + srow) * D_DIM + k0 + scol];
            float4 b0 = *(const float4*)srcB;
            float4 b1 = *(const float4*)(srcB + 4);
            uint4 pb;
            pb.x = (unsigned)f2bf(b0.x) | ((unsigned)f2bf(b0.y) << 16);
            pb.y = (unsigned)f2bf(b0.z) | ((unsigned)f2bf(b0.w) << 16);
            pb.z = (unsigned)f2bf(b1.x) | ((unsigned)f2bf(b1.y) << 16);
            pb.w = (unsigned)f2bf(b1.z) | ((unsigned)f2bf(b1.w) << 16);
            *(uint4*)&Bs[srow * 40 + scol] = pb;
        }
        __syncthreads();
        s16x8 af = *(const s16x8*)&As[(wave * 16 + l15) * 40 + quad * 8];
#pragma unroll
        for (int nt = 0; nt < 4; ++nt) {
            s16x8 bf = *(const s16x8*)&Bs[(nt * 16 + l15) * 40 + quad * 8];
            acc[nt] = __builtin_amdgcn_mfma_f32_16x16x32_bf16(af, bf, acc[nt], 0, 0, 0);
        }
    }
#pragma unroll
    for (int nt = 0; nt < 4; ++nt) {
#pragma unroll
        for (int rg = 0; rg < 4; ++rg) {
            int row = m0 + wave * 16 + quad * 4 + rg;
            int col = n0 + nt * 16 + l15;
            out[(size_t)row * N_DIM + col] = acc[nt][rg];
        }
    }
}

// ---------------- k row-normalization (in place) ---------------------------
__global__ __launch_bounds__(256) void knorm(float* __restrict__ kbuf)
{
    const int wave = threadIdx.x >> 6;
    const int lane = threadIdx.x & 63;
    const int row  = blockIdx.x * 4 + wave;
    float* p = &kbuf[(size_t)row * N_DIM + lane * 8];
    float4 a = *(const float4*)p;
    float4 b = *(const float4*)(p + 4);
    float s = a.x*a.x + a.y*a.y + a.z*a.z + a.w*a.w
            + b.x*b.x + b.y*b.y + b.z*b.z + b.w*b.w;
#pragma unroll
    for (int m = 1; m < 64; m <<= 1) s += __shfl_xor(s, m, 64);
    float inv = 1.0f / (sqrtf(s) + 1e-6f);
    a.x *= inv; a.y *= inv; a.z *= inv; a.w *= inv;
    b.x *= inv; b.y *= inv; b.z *= inv; b.w *= inv;
    *(float4*)p = a;
    *(float4*)(p + 4) = b;
}

// ---------------- sequential scan ------------------------------------------
// grid(32, 16): x = 16-row chunk, y = batch. block 256.
// R7: 16-LANE ROW GROUPS - no ds_swizzle in the reduction.
// R4/R5/R6 triangulation: adding issue work costs 1:1 (R4,R5) but removing it
// refunds nothing (R6) -> a serial latency chain sits just under the issue
// level. The untouched chain components were the 2 ds_swizzle LDS round-trips
// (~120cy each, m117) inside the per-step reductions. New mapping: each
// 16-lane DPP row owns ONE S-row x 32 cols/lane; the col-reduction is the
// pure-DPP 4-hop reduce16 (VALU pipe only). Reductions/thread 4->2, DPP ops
// 20->8, ds_swizzle 4->0.
// LDS read: lane l4 reads its own chunk l4 (32 contiguous words at 36*l4),
// 8x b128; 2-way bank alias (free, m136) x 4-way same-address broadcast
// across the wave's 4 groups. Staging layout + barrier structure unchanged.
// Prefetch uses incremental pointer bumps (no per-step 64-bit addr mul).
__global__ __launch_bounds__(256) void scan_kernel(
    const float* __restrict__ kbuf, const float* __restrict__ vbuf,
    const float* __restrict__ qbuf, float* __restrict__ out)
{
    __shared__ __align__(16) float ks[2][576];
    __shared__ __align__(16) float qs[2][576];
    __shared__ float vs[2][16];

    const int tid = threadIdx.x;
    const int l4  = tid & 15;          // lane within row-group: cols [32*l4, 32*l4+32)
    const int g   = tid >> 4;          // row-group id = local row 0..15
    const int b   = blockIdx.y;
    const int i0  = blockIdx.x * 16;

    // staging: thread writes logical cols {2tid, 2tid+1}: chunk=(2tid)>>5,
    // off=(2tid)&31 -> b64 write, conflict-free phases (R1-proven).
    const int wA  = 36 * (tid >> 4) + ((2 * tid) & 31);
    // read: lane l4 reads chunk l4 = cols [32*l4..32*l4+31], contiguous words.
    const int rA2 = 36 * l4;

    f32x2 S2[16];
#pragma unroll
    for (int u = 0; u < 16; ++u) S2[u] = (f32x2)0.0f;

    const int DT = B_DIM * N_DIM;
    const float* kp = kbuf + (size_t)b * N_DIM + 2 * tid;
    const float* qp = qbuf + (size_t)b * N_DIM + 2 * tid;
    const float* vp = vbuf + (size_t)b * N_DIM + i0 + tid;

    float2 pk, pq; float pv = 0.0f;
    {   // stage t=0 into buf0; prefetch t=1 into regs
        pk = *(const float2*)kp; kp += DT;
        pq = *(const float2*)qp; qp += DT;
        if (tid < 16) pv = *vp;
        vp += DT;
        *(float2*)&ks[0][wA] = pk;
        *(float2*)&qs[0][wA] = pq;
        if (tid < 16) vs[0][tid] = pv;
        pk = *(const float2*)kp; kp += DT;
        pq = *(const float2*)qp; qp += DT;
        if (tid < 16) pv = *vp;
        vp += DT;
    }
    __syncthreads();

    float* op = out + (size_t)b * N_DIM + i0 + g;

    const f32x2 Cv   = {C_FOLD, C_FOLD};
    const f32x2 M2Cv = {-2.0f * C_FOLD, -2.0f * C_FOLD};

    for (int t = 0; t < T_DIM; ++t) {
        const int cb = t & 1, nb = cb ^ 1;

        // stage t+1 (already in regs) into the other buffer
        if (t + 1 < T_DIM) {
            *(float2*)&ks[nb][wA] = pk;
            *(float2*)&qs[nb][wA] = pq;
            if (tid < 16) vs[nb][tid] = pv;
        }
        // issue global prefetch for t+2
        if (t + 2 < T_DIM) {
            pk = *(const float2*)kp;
            pq = *(const float2*)qp;
            if (tid < 16) pv = *vp;
        }
        kp += DT; qp += DT; vp += DT;

        f32x2 k2[16], q2[16];
#pragma unroll
        for (int u = 0; u < 8; ++u) {
            f32x4 kv = *(const f32x4*)&ks[cb][rA2 + 4 * u];
            f32x4 qv = *(const f32x4*)&qs[cb][rA2 + 4 * u];
            k2[2*u] = kv.xy; k2[2*u+1] = kv.zw;
            q2[2*u] = qv.xy; q2[2*u+1] = qv.zw;
        }
        const float v0 = vs[cb][g];

        // racc' = sum_j S'_ij k_j : 32 in-thread cols, then 16-lane DPP reduce
        f32x2 p0 = (f32x2)0.0f, p1 = (f32x2)0.0f;
        f32x2 p2 = (f32x2)0.0f, p3 = (f32x2)0.0f;
#pragma unroll
        for (int w = 0; w < 4; ++w) {
            p0 += S2[4*w]     * k2[4*w];
            p1 += S2[4*w + 1] * k2[4*w + 1];
            p2 += S2[4*w + 2] * k2[4*w + 2];
            p3 += S2[4*w + 3] * k2[4*w + 3];
        }
        p0 += p1; p2 += p3; p0 += p2;
        const float racc = reduce16(p0.x + p0.y);

        const float dp = __builtin_fmaf(C_FOLD, v0, -racc);
        const f32x2 d0 = {dp, dp};

        // S'_new = C - 2C/(exp2(S' + dp'*k)+1);  sq' += S'_new * q
        // Grouped rcp (R6): one v_rcp per 8 elems via prefix/suffix products.
        f32x2 sacc0 = (f32x2)0.0f, sacc1 = (f32x2)0.0f;
#pragma unroll
        for (int w = 0; w < 4; ++w) {
            f32x2 a0 = S2[4*w]     + d0 * k2[4*w];
            f32x2 a1 = S2[4*w + 1] + d0 * k2[4*w + 1];
            f32x2 a2 = S2[4*w + 2] + d0 * k2[4*w + 2];
            f32x2 a3 = S2[4*w + 3] + d0 * k2[4*w + 3];
            f32x2 f0 = { __builtin_amdgcn_exp2f(a0.x), __builtin_amdgcn_exp2f(a0.y) };
            f32x2 f1 = { __builtin_amdgcn_exp2f(a1.x), __builtin_amdgcn_exp2f(a1.y) };
            f32x2 f2 = { __builtin_amdgcn_exp2f(a2.x), __builtin_amdgcn_exp2f(a2.y) };
            f32x2 f3 = { __builtin_amdgcn_exp2f(a3.x), __builtin_amdgcn_exp2f(a3.y) };
            f0 = f0 + 1.0f; f1 = f1 + 1.0f; f2 = f2 + 1.0f; f3 = f3 + 1.0f;
            // product tree over the 8 scalars {f0,f1,f2,f3}.{x,y}
            f32x2 m0 = f0 * f1;
            f32x2 m1 = f2 * f3;
            f32x2 qq = m0 * m1;
            float rP = __builtin_amdgcn_rcpf(qq.x * qq.y);
            f32x2 rq  = { qq.y * rP, qq.x * rP };   // {1/qq.x, 1/qq.y}
            f32x2 rm0 = rq * m1;                     // {1/m0.x, 1/m0.y}
            f32x2 rm1 = rq * m0;                     // {1/m1.x, 1/m1.y}
            f32x2 r0 = rm0 * f1;                     // 1/f0
            f32x2 r1 = rm0 * f0;                     // 1/f1
            f32x2 r2 = rm1 * f3;                     // 1/f2
            f32x2 r3 = rm1 * f2;                     // 1/f3
            f32x2 n0 = Cv + r0 * M2Cv;
            f32x2 n1 = Cv + r1 * M2Cv;
            f32x2 n2 = Cv + r2 * M2Cv;
            f32x2 n3 = Cv + r3 * M2Cv;
            S2[4*w] = n0; S2[4*w + 1] = n1; S2[4*w + 2] = n2; S2[4*w + 3] = n3;
            sacc0 += n0 * q2[4*w]     + n2 * q2[4*w + 2];
            sacc1 += n1 * q2[4*w + 1] + n3 * q2[4*w + 3];
        }
        sacc0 += sacc1;
        const float sq = reduce16(sacc0.x + sacc0.y);

        if (l4 == 0) {
            float s0 = sq * INV_C;
            float g0 = __builtin_amdgcn_rcpf(1.0f + __builtin_amdgcn_exp2f(-s0 * 1.44269504f));
            op[0] = s0 * s0 * g0;
        }
        op += DT;
        __syncthreads();
    }

    // S_final (true scale) -> d_out[T*B*N + ((b*N + i)*N + col)]
    const size_t base = (size_t)T_DIM * B_DIM * N_DIM;
    const size_t so = base + ((size_t)b * N_DIM + i0 + g) * N_DIM + 32 * l4;
#pragma unroll
    for (int u = 0; u < 8; ++u) {
        float4 w0;
        w0.x = S2[2*u].x   * INV_C; w0.y = S2[2*u].y   * INV_C;
        w0.z = S2[2*u+1].x * INV_C; w0.w = S2[2*u+1].y * INV_C;
        *(float4*)&out[so + 4 * u] = w0;
    }
}

extern "C" void kernel_launch(void* const* d_in, const int* in_sizes, int n_in,
                              void* d_out, int out_size, void* d_ws, size_t ws_size,
                              hipStream_t stream) {
    const float* x  = (const float*)d_in[0];
    const float* Wk = (const float*)d_in[1];
    const float* Wv = (const float*)d_in[2];
    const float* Wq = (const float*)d_in[3];
    float* outp = (float*)d_out;

    const size_t MN = (size_t)T_DIM * B_DIM * N_DIM;
    float* kbuf = (float*)d_ws;
    float* vbuf = kbuf + MN;
    float* qbuf = vbuf + MN;

    proj_gemm<<<dim3(128, 8, 3), 256, 0, stream>>>(x, Wk, Wv, Wq, kbuf, vbuf, qbuf);
    knorm<<<2048, 256, 0, stream>>>(kbuf);
    scan_kernel<<<dim3(32, 16), 256, 0, stream>>>(kbuf, vbuf, qbuf, outp);
}